// Round 10
// baseline (387.775 us; speedup 1.0000x reference)
//
#include <hip/hip_runtime.h>
#include <hip/hip_bf16.h>

// RGCN layer, MI355X — round 10.
// r9: 353us, conv+resid 103us (3 blk/CU, latency-bound), tail ~250us hidden.
// This round: conv 64x64 col-split tiles -> 33KB LDS -> 4 blk/CU (same
// async16/NT pattern, shorter barrier chain, 2x blocks; sibling half-block
// re-reads A from L2); prep2 folded into prep3 (scanC self-prefix) -> 7
// nodes; reduce 8-deep load pipeline.

#define N_NODES 20000
#define E_EDGES 640000
#define R_REL   65
#define TM      64
#define NB_RESID 626          // 313 row-tiles x 2 col-halves
#define NB_EDGE  20608        // 2 * max tiles
#define SCAT_CH 2560

typedef __attribute__((ext_vector_type(8))) short bf16x8;
typedef __attribute__((ext_vector_type(4))) float f32x4;
typedef __attribute__((ext_vector_type(4))) unsigned int u32x4;
typedef __attribute__((ext_vector_type(2))) unsigned int u32x2;

__device__ __forceinline__ unsigned short f2bf(float x) {
    union { float f; unsigned int u; } c; c.f = x;
    unsigned int b = c.u + 0x7fffu + ((c.u >> 16) & 1u);   // RTNE
    return (unsigned short)(b >> 16);
}
__device__ __forceinline__ float bf2f_lo(unsigned int u) {
    union { unsigned int u; float f; } c; c.u = u << 16; return c.f;
}
__device__ __forceinline__ float bf2f_hi(unsigned int u) {
    union { unsigned int u; float f; } c; c.u = u & 0xffff0000u; return c.f;
}
__device__ __forceinline__ void async16(const void* g, void* l) {
    __builtin_amdgcn_global_load_lds(
        (const __attribute__((address_space(1))) unsigned int*)g,
        (__attribute__((address_space(3))) unsigned int*)l, 16, 0, 0);
}
__device__ __forceinline__ int unperm(int p) {      // permuted pos -> true col
    return (p & 64) + ((p & 3) << 4) + ((p >> 2) & 15);
}

// ---------------- K1: basis GEMM || etype+dst hist || f32->bf16 cvt --------
__global__ void k_prep1(const float* __restrict__ comp, const float* __restrict__ basis,
                        float* __restrict__ W32, const int* __restrict__ et,
                        const int* __restrict__ dstA, int* __restrict__ ghist,
                        int* __restrict__ gh2, const float* __restrict__ node_feats,
                        unsigned short* __restrict__ node_bf) {
    __shared__ float lc[16 * 65];
    __shared__ int lh[R_REL];
    int b = blockIdx.x, t = threadIdx.x;
    if (b < 320) {                                  // basis GEMM
        int r0 = (b >> 6) * 16;
        int col = (b & 63) * 256 + t;
        for (int j = t; j < 16 * 65; j += 256) {
            int rr = r0 + j / 65;
            lc[j] = (rr < R_REL) ? comp[rr * 65 + (j % 65)] : 0.f;
        }
        __syncthreads();
        float acc[16];
#pragma unroll
        for (int j = 0; j < 16; ++j) acc[j] = 0.f;
        for (int k = 0; k < 65; ++k) {
            float v = basis[k * 16384 + col];
#pragma unroll
            for (int j = 0; j < 16; ++j) acc[j] += lc[j * 65 + k] * v;
        }
#pragma unroll
        for (int j = 0; j < 16; ++j) {
            int rr = r0 + j;
            if (rr < R_REL) W32[rr * 16384 + col] = acc[j];
        }
    } else if (b < 832) {                           // histograms
        if (t < R_REL) lh[t] = 0;
        __syncthreads();
        for (int i = (b - 320) * 256 + t; i < E_EDGES; i += 512 * 256) {
            atomicAdd(&lh[et[i]], 1);
            atomicAdd(&gh2[dstA[i]], 1);
        }
        __syncthreads();
        if (t < R_REL) atomicAdd(&ghist[t], lh[t]);
    } else {                                        // cvt fp32 -> bf16 (x4)
        int i = (b - 832) * 256 + t;
        if (i < N_NODES * 32) {
            float4 v = reinterpret_cast<const float4*>(node_feats)[i];
            __hip_bfloat162 b0 = __float22bfloat162_rn(make_float2(v.x, v.y));
            __hip_bfloat162 b1 = __float22bfloat162_rn(make_float2(v.z, v.w));
            u32x2 pk;
            pk.x = *reinterpret_cast<unsigned int*>(&b0);
            pk.y = *reinterpret_cast<unsigned int*>(&b1);
            reinterpret_cast<u32x2*>(node_bf)[i] = pk;
        }
    }
}

// ---------------- K2: scanC (self prefix) || tiles || transposes -----------
__global__ void k_prep3(const int* __restrict__ gh2, int* __restrict__ cnt2,
                        int* __restrict__ seg, const int* __restrict__ ghist,
                        int* __restrict__ cnt, int* __restrict__ ntiles_p,
                        int* __restrict__ tile_rel, int* __restrict__ tile_start,
                        int* __restrict__ tile_len, const float* __restrict__ W32,
                        unsigned short* __restrict__ Wt, const float* __restrict__ Wresf,
                        unsigned short* __restrict__ Wrest) {
    int b = blockIdx.x, t = threadIdx.x;
    if (b < 80) {                                   // scanC with self-prefix
        __shared__ int red[256];
        __shared__ int pref;
        int acc = 0;
        for (int i = t; i < b * 256; i += 256) acc += gh2[i];
        red[t] = acc;
        __syncthreads();
        for (int off = 128; off > 0; off >>= 1) {
            if (t < off) red[t] += red[t + off];
            __syncthreads();
        }
        if (t == 0) pref = red[0];
        __syncthreads();
        int i = b * 256 + t;
        int v = (i < N_NODES) ? gh2[i] : 0;
        red[t] = v;
        __syncthreads();
        for (int off = 1; off < 256; off <<= 1) {
            int x = (t >= off) ? red[t - off] : 0;
            __syncthreads();
            red[t] += x;
            __syncthreads();
        }
        int excl = red[t] - v + pref;
        if (i < N_NODES) {
            cnt2[i] = excl;
            seg[i] = excl;
            if (i == N_NODES - 1) seg[N_NODES] = excl + v;
        }
    } else if (b == 80) {                           // ghist scan + tile descs
        __shared__ int base[R_REL + 1], tbase[R_REL + 1];
        int lane = t & 63;
        if (t < 64) {
            int v = ghist[lane];
            int x = v;
#pragma unroll
            for (int off = 1; off < 64; off <<= 1) {
                int y = __shfl_up(x, off);
                if (lane >= off) x += y;
            }
            base[lane] = x - v;
            if (lane == 63) {
                base[64] = x;
                base[65] = x + ghist[64];
            }
        }
        __syncthreads();
        if (t == 0) {
            int tb = 0;
            for (int r = 0; r < R_REL; ++r) {
                tbase[r] = tb;
                tb += (base[r + 1] - base[r] + TM - 1) / TM;
            }
            *ntiles_p = tb;
        }
        __syncthreads();
        if (t < R_REL) {
            cnt[t] = base[t];
            int s = base[t], e = base[t + 1], j = tbase[t];
            while (s < e) {
                int len = min(TM, e - s);
                tile_rel[j] = t; tile_start[j] = s; tile_len[j] = len;
                ++j; s += len;
            }
        }
    } else {                                        // transposes (264 blocks)
        __shared__ float tile[64][65];
        int bb = b - 81;
        const float* s; unsigned short* d; int sub;
        if (bb < R_REL * 4) { s = W32 + (size_t)(bb >> 2) * 16384; d = Wt + (size_t)(bb >> 2) * 16384; sub = bb & 3; }
        else { s = Wresf; d = Wrest; sub = bb - R_REL * 4; }
        int ot = (sub >> 1) & 1, itl = sub & 1;
        int tx = t & 63, ty = t >> 6;
        for (int it = 0; it < 16; ++it) {
            int i = ty + it * 4;
            tile[i][tx] = s[(itl * 64 + i) * 128 + ot * 64 + tx];
        }
        __syncthreads();
        for (int it = 0; it < 16; ++it) {
            int o = ty + it * 4;
            d[(ot * 64 + o) * 128 + itl * 64 + tx] = f2bf(tile[tx][o]);
        }
    }
}

// ---------------- K3: rel scatter + dst-position assignment ----------------
__global__ void k_scatter2(const int* __restrict__ et, const int* __restrict__ srcA,
                           const int* __restrict__ dstA, const float* __restrict__ norm,
                           int* __restrict__ cnt, int* __restrict__ cnt2,
                           int* __restrict__ srcp, float* __restrict__ normp,
                           int* __restrict__ inv2) {
    __shared__ int lh[R_REL], lbase[R_REL];
    int c0 = blockIdx.x * SCAT_CH;
    int cend = min(c0 + SCAT_CH, E_EDGES);
    if (threadIdx.x < R_REL) lh[threadIdx.x] = 0;
    __syncthreads();
    for (int i = c0 + threadIdx.x; i < cend; i += 256) atomicAdd(&lh[et[i]], 1);
    __syncthreads();
    if (threadIdx.x < R_REL && lh[threadIdx.x] > 0)
        lbase[threadIdx.x] = atomicAdd(&cnt[threadIdx.x], lh[threadIdx.x]);
    __syncthreads();
    if (threadIdx.x < R_REL) lh[threadIdx.x] = 0;
    __syncthreads();
    for (int i = c0 + threadIdx.x; i < cend; i += 256) {
        int r = et[i];
        int p = lbase[r] + atomicAdd(&lh[r], 1);
        srcp[p] = srcA[i];
        normp[p] = norm[i];
        inv2[p] = atomicAdd(&cnt2[dstA[i]], 1);
    }
}

// ---------------- K4: 64x64 tiles: resid halves + edge GEMM halves ---------
// LDS 33KB -> 4 blocks/CU. blockIdx<626: resid (rt=b>>1, half=b&1);
// else edge tile (tid=(b-626)>>1, half=(b-626)&1). async16 staging, 1
// barrier, NT stores, r5 pattern.
__global__ __launch_bounds__(256, 4) void k_conv_gemm(
    const int* __restrict__ tile_rel, const int* __restrict__ tile_start,
    const int* __restrict__ tile_len, const int* __restrict__ ntiles_p,
    const int* __restrict__ srcp, const float* __restrict__ normp,
    const unsigned short* __restrict__ node_bf,
    const unsigned short* __restrict__ Wt, const unsigned short* __restrict__ Wrest,
    const float* __restrict__ b_res, const int* __restrict__ inv2,
    unsigned short* __restrict__ t_out, float* __restrict__ resid) {
    __shared__ unsigned short Alds[64 * 128];
    __shared__ unsigned short Blds[64 * 128];
    __shared__ float snorm[64];
    __shared__ int sp2[64];
    int t = threadIdx.x;
    int w = t >> 6, lane = t & 63;
    int lrow = lane & 15, quad = lane >> 4;

    if (blockIdx.x < NB_RESID) {
        // ---- residual half-tile: 64 rows x 64 cols
        int rt = blockIdx.x >> 1, half = blockIdx.x & 1;
        int row0 = rt * 64, wc = half * 64;
        int nrows = min(64, N_NODES - row0);
#pragma unroll
        for (int it = 0; it < 4; ++it) {            // W-half rows wc..wc+63
            int j = t + 256 * it;
            int o = j >> 4, c = j & 15, cs = c ^ (o & 15);
            async16(Wrest + (size_t)(wc + o) * 128 + cs * 8, &Blds[o * 128 + c * 8]);
        }
#pragma unroll
        for (int it = 0; it < 4; ++it) {            // A rows
            int j = t + 256 * it;
            int p = j >> 4, c = j & 15, cs = c ^ (p & 15);
            if (p < nrows)
                async16(node_bf + (size_t)(row0 + p) * 128 + cs * 8,
                        &Alds[p * 128 + c * 8]);
        }
        __syncthreads();
        f32x4 acc[4];
#pragma unroll
        for (int j = 0; j < 4; ++j) acc[j] = (f32x4){0.f, 0.f, 0.f, 0.f};
#pragma unroll
        for (int ks = 0; ks < 4; ++ks) {
            int cs = (ks * 4 + quad) ^ lrow;
            bf16x8 af = *reinterpret_cast<const bf16x8*>(&Alds[(w * 16 + lrow) * 128 + cs * 8]);
#pragma unroll
            for (int j = 0; j < 4; ++j) {
                bf16x8 bf = *reinterpret_cast<const bf16x8*>(&Blds[(j * 16 + lrow) * 128 + cs * 8]);
                acc[j] = __builtin_amdgcn_mfma_f32_16x16x32_bf16(af, bf, acc[j], 0, 0, 0);
            }
        }
        float br0 = b_res[wc + lrow];
        float br1 = b_res[wc + 16 + lrow];
        float br2 = b_res[wc + 32 + lrow];
        float br3 = b_res[wc + 48 + lrow];
#pragma unroll
        for (int reg = 0; reg < 4; ++reg) {
            int grow = row0 + w * 16 + quad * 4 + reg;
            if (grow < N_NODES) {
                float4 v;
                v.x = fmaxf(acc[0][reg] + br0, 0.f);
                v.y = fmaxf(acc[1][reg] + br1, 0.f);
                v.z = fmaxf(acc[2][reg] + br2, 0.f);
                v.w = fmaxf(acc[3][reg] + br3, 0.f);
                *reinterpret_cast<float4*>(resid + (size_t)grow * 128 + wc + lrow * 4) = v;
            }
        }
        return;
    }

    // ---- edge half-tile
    int q = blockIdx.x - NB_RESID;
    int tid = q >> 1, half = q & 1;
    if (tid >= *ntiles_p) return;
    int r = tile_rel[tid], start = tile_start[tid], len = tile_len[tid];
    int wc = half * 64;
    const unsigned short* Wr = Wt + (size_t)r * 16384 + (size_t)wc * 128;
#pragma unroll
    for (int it = 0; it < 4; ++it) {               // stage W-half
        int j = t + 256 * it;
        int o = j >> 4, c = j & 15, cs = c ^ (o & 15);
        async16(Wr + o * 128 + cs * 8, &Blds[o * 128 + c * 8]);
    }
#pragma unroll
    for (int it = 0; it < 4; ++it) {               // stage A (gathered rows)
        int j = t + 256 * it;
        int p = j >> 4, c = j & 15, cs = c ^ (p & 15);
        if (p < len)
            async16(node_bf + (size_t)srcp[start + p] * 128 + cs * 8,
                    &Alds[p * 128 + c * 8]);
    }
    if (t < TM && t < len) {
        snorm[t] = normp[start + t];
        sp2[t] = inv2[start + t];
    }
    __syncthreads();

    f32x4 acc[4];
#pragma unroll
    for (int j = 0; j < 4; ++j) acc[j] = (f32x4){0.f, 0.f, 0.f, 0.f};
#pragma unroll
    for (int ks = 0; ks < 4; ++ks) {
        int cs = (ks * 4 + quad) ^ lrow;
        bf16x8 af = *reinterpret_cast<const bf16x8*>(&Alds[(w * 16 + lrow) * 128 + cs * 8]);
#pragma unroll
        for (int j = 0; j < 4; ++j) {
            bf16x8 bf = *reinterpret_cast<const bf16x8*>(&Blds[(j * 16 + lrow) * 128 + cs * 8]);
            acc[j] = __builtin_amdgcn_mfma_f32_16x16x32_bf16(af, bf, acc[j], 0, 0, 0);
        }
    }

    // epilogue: scale by norm, pack bf16, NT-store permuted row chunk
#pragma unroll
    for (int reg = 0; reg < 4; ++reg) {
        int m = w * 16 + quad * 4 + reg;
        if (m < len) {
            float nm = snorm[m];
            int p2 = sp2[m];
            float2 lo2 = make_float2(acc[0][reg] * nm, acc[1][reg] * nm);
            float2 hi2 = make_float2(acc[2][reg] * nm, acc[3][reg] * nm);
            __hip_bfloat162 blo = __float22bfloat162_rn(lo2);
            __hip_bfloat162 bhi = __float22bfloat162_rn(hi2);
            u32x2 st;
            st.x = *reinterpret_cast<unsigned int*>(&blo);
            st.y = *reinterpret_cast<unsigned int*>(&bhi);
            __builtin_nontemporal_store(st,
                reinterpret_cast<u32x2*>(t_out + (size_t)p2 * 128 + wc + lrow * 4));
        }
    }
}

// ---------------- K5: wave-per-dst CSR reduce, 8-deep MLP ------------------
__global__ __launch_bounds__(256) void k_reduce_fused(
    const unsigned short* __restrict__ t, const int* __restrict__ seg,
    const float* __restrict__ resid, const float* __restrict__ h_bias,
    float* __restrict__ h, float* __restrict__ colsum, float* __restrict__ colsumsq) {
    __shared__ float cs1[128], cs2[128], sbias[128];
    if (threadIdx.x < 128) {
        cs1[threadIdx.x] = 0.f; cs2[threadIdx.x] = 0.f;
        sbias[threadIdx.x] = h_bias[unperm(threadIdx.x)];
    }
    __syncthreads();
    int w = threadIdx.x >> 6, lane = threadIdx.x & 63;
    int g = lane >> 4, c = lane & 15;
    for (int k = 0; k < 4; ++k) {
        int d = blockIdx.x * 16 + k * 4 + w;
        int a = seg[d], b = seg[d + 1];
        float s[8];
#pragma unroll
        for (int kk = 0; kk < 8; ++kk) s[kk] = 0.f;
        int q = a + g;
        for (; q + 28 < b; q += 32) {
            u32x4 v0 = __builtin_nontemporal_load(reinterpret_cast<const u32x4*>(t + (size_t)q * 128 + c * 8));
            u32x4 v1 = __builtin_nontemporal_load(reinterpret_cast<const u32x4*>(t + (size_t)(q + 4) * 128 + c * 8));
            u32x4 v2 = __builtin_nontemporal_load(reinterpret_cast<const u32x4*>(t + (size_t)(q + 8) * 128 + c * 8));
            u32x4 v3 = __builtin_nontemporal_load(reinterpret_cast<const u32x4*>(t + (size_t)(q + 12) * 128 + c * 8));
            u32x4 v4 = __builtin_nontemporal_load(reinterpret_cast<const u32x4*>(t + (size_t)(q + 16) * 128 + c * 8));
            u32x4 v5 = __builtin_nontemporal_load(reinterpret_cast<const u32x4*>(t + (size_t)(q + 20) * 128 + c * 8));
            u32x4 v6 = __builtin_nontemporal_load(reinterpret_cast<const u32x4*>(t + (size_t)(q + 24) * 128 + c * 8));
            u32x4 v7 = __builtin_nontemporal_load(reinterpret_cast<const u32x4*>(t + (size_t)(q + 28) * 128 + c * 8));
#pragma unroll
            for (int kk = 0; kk < 4; ++kk) {
                s[2 * kk]     += bf2f_lo(v0[kk]) + bf2f_lo(v1[kk]) + bf2f_lo(v2[kk]) + bf2f_lo(v3[kk])
                               + bf2f_lo(v4[kk]) + bf2f_lo(v5[kk]) + bf2f_lo(v6[kk]) + bf2f_lo(v7[kk]);
                s[2 * kk + 1] += bf2f_hi(v0[kk]) + bf2f_hi(v1[kk]) + bf2f_hi(v2[kk]) + bf2f_hi(v3[kk])
                               + bf2f_hi(v4[kk]) + bf2f_hi(v5[kk]) + bf2f_hi(v6[kk]) + bf2f_hi(v7[kk]);
            }
        }
        for (; q < b; q += 4) {
            u32x4 v = __builtin_nontemporal_load(reinterpret_cast<const u32x4*>(t + (size_t)q * 128 + c * 8));
#pragma unroll
            for (int kk = 0; kk < 4; ++kk) {
                s[2 * kk]     += bf2f_lo(v[kk]);
                s[2 * kk + 1] += bf2f_hi(v[kk]);
            }
        }
#pragma unroll
        for (int kk = 0; kk < 8; ++kk) {
            s[kk] += __shfl_xor(s[kk], 16);
            s[kk] += __shfl_xor(s[kk], 32);
        }
        if (g == 0) {
            const float* rp = resid + (size_t)d * 128 + c * 8;
            float4 r0 = *reinterpret_cast<const float4*>(rp);
            float4 r1 = *reinterpret_cast<const float4*>(rp + 4);
            float rr[8] = {r0.x, r0.y, r0.z, r0.w, r1.x, r1.y, r1.z, r1.w};
            float v[8];
#pragma unroll
            for (int kk = 0; kk < 8; ++kk)
                v[kk] = fmaxf(s[kk] + sbias[c * 8 + kk], 0.f) + rr[kk];
            float* hp = h + (size_t)d * 128 + c * 8;
            *reinterpret_cast<float4*>(hp)     = make_float4(v[0], v[1], v[2], v[3]);
            *reinterpret_cast<float4*>(hp + 4) = make_float4(v[4], v[5], v[6], v[7]);
#pragma unroll
            for (int kk = 0; kk < 8; ++kk) {
                atomicAdd(&cs1[c * 8 + kk], v[kk]);
                atomicAdd(&cs2[c * 8 + kk], v[kk] * v[kk]);
            }
        }
    }
    __syncthreads();
    if (threadIdx.x < 128) {
        atomicAdd(&colsum[threadIdx.x], cs1[threadIdx.x]);
        atomicAdd(&colsumsq[threadIdx.x], cs2[threadIdx.x]);
    }
}

// ---------------- K6: BN apply + unpermute to natural cols -----------------
__global__ void k_bn(float* __restrict__ h, const float* __restrict__ colsum,
                     const float* __restrict__ colsumsq, const float* __restrict__ gamma,
                     const float* __restrict__ beta) {
    __shared__ float sc[128], sh[128], tile[8][128];
    int t = threadIdx.x;
    if (t < 128) {
        int n = unperm(t);
        float m = colsum[t] * (1.f / N_NODES);
        float var = colsumsq[t] * (1.f / N_NODES) - m * m;
        float s = gamma[n] * rsqrtf(var + 1e-5f);
        sc[t] = s;
        sh[t] = beta[n] - m * s;
    }
    __syncthreads();
    int r = t >> 5;
    int p0 = (t & 31) * 4;
    int n0 = (p0 & 64) + ((p0 >> 2) & 15);
    for (int row0 = blockIdx.x * 8; row0 < N_NODES; row0 += gridDim.x * 8) {
        int row = row0 + r;
        float4 v = make_float4(0.f, 0.f, 0.f, 0.f);
        if (row < N_NODES) v = *reinterpret_cast<float4*>(h + (size_t)row * 128 + p0);
        v.x = v.x * sc[p0] + sh[p0];
        v.y = v.y * sc[p0 + 1] + sh[p0 + 1];
        v.z = v.z * sc[p0 + 2] + sh[p0 + 2];
        v.w = v.w * sc[p0 + 3] + sh[p0 + 3];
        tile[r][n0]      = v.x;
        tile[r][n0 + 16] = v.y;
        tile[r][n0 + 32] = v.z;
        tile[r][n0 + 48] = v.w;
        __syncthreads();
        if (row < N_NODES)
            *reinterpret_cast<float4*>(h + (size_t)row * 128 + p0) =
                *reinterpret_cast<float4*>(&tile[r][p0]);
        __syncthreads();
    }
}

extern "C" void kernel_launch(void* const* d_in, const int* in_sizes, int n_in,
                              void* d_out, int out_size, void* d_ws, size_t ws_size,
                              hipStream_t stream) {
    (void)in_sizes; (void)n_in; (void)out_size; (void)ws_size;
    const float* node_feats = (const float*)d_in[0];
    const int* src    = (const int*)d_in[1];
    const int* dst    = (const int*)d_in[2];
    const int* etype  = (const int*)d_in[3];
    const float* norm = (const float*)d_in[4];
    const float* basis = (const float*)d_in[5];
    const float* comp  = (const float*)d_in[6];
    const float* h_bias = (const float*)d_in[7];
    const float* W_res  = (const float*)d_in[8];
    const float* b_res  = (const float*)d_in[9];
    const float* gamma  = (const float*)d_in[10];
    const float* beta   = (const float*)d_in[11];

    char* ws = (char*)d_ws;
    int* ghist      = (int*)(ws + 0);
    int* cnt        = (int*)(ws + 1024);
    int* ntiles_p   = (int*)(ws + 2048);
    float* colsum   = (float*)(ws + 2560);
    float* colsumsq = (float*)(ws + 3072);
    int* gh2        = (int*)(ws + 8192);       // 80000 -> 88192
    int* tile_rel   = (int*)(ws + 88192);      // 40960
    int* tile_start = (int*)(ws + 129152);     // 40960
    int* tile_len   = (int*)(ws + 170112);     // 40960 -> 211072
    unsigned short* Wt      = (unsigned short*)(ws + 211072);    // 2129920 -> 2340992
    unsigned short* Wrest   = (unsigned short*)(ws + 2340992);   // 32768   -> 2373760
    unsigned short* node_bf = (unsigned short*)(ws + 2373760);   // 5120000 -> 7493760
    int* srcp       = (int*)(ws + 7493760);    // 2560000 -> 10053760
    float* normp    = (float*)(ws + 10053760); // 2560000 -> 12613760
    int* inv2       = (int*)(ws + 12613760);   // 2560000 -> 15173760
    float* resid    = (float*)(ws + 15173760); // 10240000 -> 25413760
    int* seg        = (int*)(ws + 25413760);   // 80004 -> 25493764, pad
    int* cnt2       = (int*)(ws + 25493776);   // 80000 -> 25573776
    const long T_BASE = 25573776L;             // 16B aligned
    float* W32      = (float*)(ws + T_BASE);   // aliased: dead before conv
    unsigned short* t_buf = (unsigned short*)(ws + T_BASE);      // 163.84 MB
    float* hacc = (float*)d_out;

    hipMemsetAsync(ws, 0, 88192, stream);
    k_prep1<<<3332, 256, 0, stream>>>(comp, basis, W32, etype, dst, ghist, gh2,
                                      node_feats, node_bf);
    k_prep3<<<345, 256, 0, stream>>>(gh2, cnt2, seg, ghist, cnt, ntiles_p,
                                     tile_rel, tile_start, tile_len,
                                     W32, Wt, W_res, Wrest);
    k_scatter2<<<(E_EDGES + SCAT_CH - 1) / SCAT_CH, 256, 0, stream>>>(
        etype, src, dst, norm, cnt, cnt2, srcp, normp, inv2);
    k_conv_gemm<<<NB_RESID + NB_EDGE, 256, 0, stream>>>(
        tile_rel, tile_start, tile_len, ntiles_p, srcp, normp, node_bf,
        Wt, Wrest, b_res, inv2, t_buf, resid);
    k_reduce_fused<<<N_NODES / 16, 256, 0, stream>>>(t_buf, seg, resid, h_bias,
                                                     hacc, colsum, colsumsq);
    k_bn<<<2500, 256, 0, stream>>>(hacc, colsum, colsumsq, gamma, beta);
}

// Round 11
// 322.986 us; speedup vs baseline: 1.2006x; 1.2006x over previous
//
#include <hip/hip_runtime.h>
#include <hip/hip_bf16.h>

// RGCN layer, MI355X — round 11.
// r10 post-mortem: col-split regressed (A gathered twice, FETCH 55->84MB).
// Conv tiles revert to r9 (64x128, 3 blk/CU, merged resid).
// NEW: t_buf stores/loads are PLAIN (not NT). Evidence: NT writes run at
// ~2.1 TB/s across r5/r6/r9/r10 = random 128B HBM scatter ceiling; t_buf
// (164MB) fits in the 256MB Infinity Cache — plain full-line stores let L3
// capture the stream and reduce reads from L3. Keep r10's 6-node pipeline
// (prep1, prep3 w/ self-prefix scan + transposes, scatter2, conv, reduce, bn)
// and 8-deep reduce load pipeline.

#define N_NODES 20000
#define E_EDGES 640000
#define R_REL   65
#define TM      64
#define NB_RESID 313
#define MAX_TILES 10240
#define SCAT_CH 2560

typedef __attribute__((ext_vector_type(8))) short bf16x8;
typedef __attribute__((ext_vector_type(4))) float f32x4;
typedef __attribute__((ext_vector_type(4))) unsigned int u32x4;
typedef __attribute__((ext_vector_type(2))) unsigned int u32x2;

__device__ __forceinline__ unsigned short f2bf(float x) {
    union { float f; unsigned int u; } c; c.f = x;
    unsigned int b = c.u + 0x7fffu + ((c.u >> 16) & 1u);   // RTNE
    return (unsigned short)(b >> 16);
}
__device__ __forceinline__ float bf2f_lo(unsigned int u) {
    union { unsigned int u; float f; } c; c.u = u << 16; return c.f;
}
__device__ __forceinline__ float bf2f_hi(unsigned int u) {
    union { unsigned int u; float f; } c; c.u = u & 0xffff0000u; return c.f;
}
__device__ __forceinline__ void async16(const void* g, void* l) {
    __builtin_amdgcn_global_load_lds(
        (const __attribute__((address_space(1))) unsigned int*)g,
        (__attribute__((address_space(3))) unsigned int*)l, 16, 0, 0);
}
__device__ __forceinline__ int unperm(int p) {      // permuted pos -> true col
    return (p & 64) + ((p & 3) << 4) + ((p >> 2) & 15);
}

// ---------------- K1: basis GEMM || etype+dst hist || f32->bf16 cvt --------
__global__ void k_prep1(const float* __restrict__ comp, const float* __restrict__ basis,
                        float* __restrict__ W32, const int* __restrict__ et,
                        const int* __restrict__ dstA, int* __restrict__ ghist,
                        int* __restrict__ gh2, const float* __restrict__ node_feats,
                        unsigned short* __restrict__ node_bf) {
    __shared__ float lc[16 * 65];
    __shared__ int lh[R_REL];
    int b = blockIdx.x, t = threadIdx.x;
    if (b < 320) {                                  // basis GEMM
        int r0 = (b >> 6) * 16;
        int col = (b & 63) * 256 + t;
        for (int j = t; j < 16 * 65; j += 256) {
            int rr = r0 + j / 65;
            lc[j] = (rr < R_REL) ? comp[rr * 65 + (j % 65)] : 0.f;
        }
        __syncthreads();
        float acc[16];
#pragma unroll
        for (int j = 0; j < 16; ++j) acc[j] = 0.f;
        for (int k = 0; k < 65; ++k) {
            float v = basis[k * 16384 + col];
#pragma unroll
            for (int j = 0; j < 16; ++j) acc[j] += lc[j * 65 + k] * v;
        }
#pragma unroll
        for (int j = 0; j < 16; ++j) {
            int rr = r0 + j;
            if (rr < R_REL) W32[rr * 16384 + col] = acc[j];
        }
    } else if (b < 832) {                           // histograms
        if (t < R_REL) lh[t] = 0;
        __syncthreads();
        for (int i = (b - 320) * 256 + t; i < E_EDGES; i += 512 * 256) {
            atomicAdd(&lh[et[i]], 1);
            atomicAdd(&gh2[dstA[i]], 1);
        }
        __syncthreads();
        if (t < R_REL) atomicAdd(&ghist[t], lh[t]);
    } else {                                        // cvt fp32 -> bf16 (x4)
        int i = (b - 832) * 256 + t;
        if (i < N_NODES * 32) {
            float4 v = reinterpret_cast<const float4*>(node_feats)[i];
            __hip_bfloat162 b0 = __float22bfloat162_rn(make_float2(v.x, v.y));
            __hip_bfloat162 b1 = __float22bfloat162_rn(make_float2(v.z, v.w));
            u32x2 pk;
            pk.x = *reinterpret_cast<unsigned int*>(&b0);
            pk.y = *reinterpret_cast<unsigned int*>(&b1);
            reinterpret_cast<u32x2*>(node_bf)[i] = pk;
        }
    }
}

// ---------------- K2: scanC (self prefix) || tiles || transposes -----------
__global__ void k_prep3(const int* __restrict__ gh2, int* __restrict__ cnt2,
                        int* __restrict__ seg, const int* __restrict__ ghist,
                        int* __restrict__ cnt, int* __restrict__ ntiles_p,
                        int* __restrict__ tile_rel, int* __restrict__ tile_start,
                        int* __restrict__ tile_len, const float* __restrict__ W32,
                        unsigned short* __restrict__ Wt, const float* __restrict__ Wresf,
                        unsigned short* __restrict__ Wrest) {
    int b = blockIdx.x, t = threadIdx.x;
    if (b < 80) {                                   // scanC with self-prefix
        __shared__ int red[256];
        __shared__ int pref;
        int acc = 0;
        for (int i = t; i < b * 256; i += 256) acc += gh2[i];
        red[t] = acc;
        __syncthreads();
        for (int off = 128; off > 0; off >>= 1) {
            if (t < off) red[t] += red[t + off];
            __syncthreads();
        }
        if (t == 0) pref = red[0];
        __syncthreads();
        int i = b * 256 + t;
        int v = (i < N_NODES) ? gh2[i] : 0;
        red[t] = v;
        __syncthreads();
        for (int off = 1; off < 256; off <<= 1) {
            int x = (t >= off) ? red[t - off] : 0;
            __syncthreads();
            red[t] += x;
            __syncthreads();
        }
        int excl = red[t] - v + pref;
        if (i < N_NODES) {
            cnt2[i] = excl;
            seg[i] = excl;
            if (i == N_NODES - 1) seg[N_NODES] = excl + v;
        }
    } else if (b == 80) {                           // ghist scan + tile descs
        __shared__ int base[R_REL + 1], tbase[R_REL + 1];
        int lane = t & 63;
        if (t < 64) {
            int v = ghist[lane];
            int x = v;
#pragma unroll
            for (int off = 1; off < 64; off <<= 1) {
                int y = __shfl_up(x, off);
                if (lane >= off) x += y;
            }
            base[lane] = x - v;
            if (lane == 63) {
                base[64] = x;
                base[65] = x + ghist[64];
            }
        }
        __syncthreads();
        if (t == 0) {
            int tb = 0;
            for (int r = 0; r < R_REL; ++r) {
                tbase[r] = tb;
                tb += (base[r + 1] - base[r] + TM - 1) / TM;
            }
            *ntiles_p = tb;
        }
        __syncthreads();
        if (t < R_REL) {
            cnt[t] = base[t];
            int s = base[t], e = base[t + 1], j = tbase[t];
            while (s < e) {
                int len = min(TM, e - s);
                tile_rel[j] = t; tile_start[j] = s; tile_len[j] = len;
                ++j; s += len;
            }
        }
    } else {                                        // transposes (264 blocks)
        __shared__ float tile[64][65];
        int bb = b - 81;
        const float* s; unsigned short* d; int sub;
        if (bb < R_REL * 4) { s = W32 + (size_t)(bb >> 2) * 16384; d = Wt + (size_t)(bb >> 2) * 16384; sub = bb & 3; }
        else { s = Wresf; d = Wrest; sub = bb - R_REL * 4; }
        int ot = (sub >> 1) & 1, itl = sub & 1;
        int tx = t & 63, ty = t >> 6;
        for (int it = 0; it < 16; ++it) {
            int i = ty + it * 4;
            tile[i][tx] = s[(itl * 64 + i) * 128 + ot * 64 + tx];
        }
        __syncthreads();
        for (int it = 0; it < 16; ++it) {
            int o = ty + it * 4;
            d[(ot * 64 + o) * 128 + itl * 64 + tx] = f2bf(tile[tx][o]);
        }
    }
}

// ---------------- K3: rel scatter + dst-position assignment ----------------
__global__ void k_scatter2(const int* __restrict__ et, const int* __restrict__ srcA,
                           const int* __restrict__ dstA, const float* __restrict__ norm,
                           int* __restrict__ cnt, int* __restrict__ cnt2,
                           int* __restrict__ srcp, float* __restrict__ normp,
                           int* __restrict__ inv2) {
    __shared__ int lh[R_REL], lbase[R_REL];
    int c0 = blockIdx.x * SCAT_CH;
    int cend = min(c0 + SCAT_CH, E_EDGES);
    if (threadIdx.x < R_REL) lh[threadIdx.x] = 0;
    __syncthreads();
    for (int i = c0 + threadIdx.x; i < cend; i += 256) atomicAdd(&lh[et[i]], 1);
    __syncthreads();
    if (threadIdx.x < R_REL && lh[threadIdx.x] > 0)
        lbase[threadIdx.x] = atomicAdd(&cnt[threadIdx.x], lh[threadIdx.x]);
    __syncthreads();
    if (threadIdx.x < R_REL) lh[threadIdx.x] = 0;
    __syncthreads();
    for (int i = c0 + threadIdx.x; i < cend; i += 256) {
        int r = et[i];
        int p = lbase[r] + atomicAdd(&lh[r], 1);
        srcp[p] = srcA[i];
        normp[p] = norm[i];
        inv2[p] = atomicAdd(&cnt2[dstA[i]], 1);
    }
}

// ---------------- K4: resid tiles + edge GEMM tiles (r9 structure) ---------
// Plain stores for t_out: 164MB fits Infinity Cache; quad writes are full
// 128B aligned lines (no fetch-on-write).
__global__ __launch_bounds__(256, 3) void k_conv_gemm(
    const int* __restrict__ tile_rel, const int* __restrict__ tile_start,
    const int* __restrict__ tile_len, const int* __restrict__ ntiles_p,
    const int* __restrict__ srcp, const float* __restrict__ normp,
    const unsigned short* __restrict__ node_bf,
    const unsigned short* __restrict__ Wt, const unsigned short* __restrict__ Wrest,
    const float* __restrict__ b_res, const int* __restrict__ inv2,
    unsigned short* __restrict__ t_out, float* __restrict__ resid) {
    __shared__ unsigned short Alds[64 * 128];
    __shared__ unsigned short Blds[128 * 128];
    __shared__ float snorm[64];
    __shared__ int sp2[64];
    int t = threadIdx.x;
    int w = t >> 6, lane = t & 63;
    int wr = (w >> 1) * 32, wc = (w & 1) * 64;
    int lrow = lane & 15, quad = lane >> 4;

    if (blockIdx.x < NB_RESID) {
        // ---- residual tile: rows row0..row0+63, relu(x@W_res+b) -> resid
        int row0 = blockIdx.x * 64;
        int nrows = min(64, N_NODES - row0);
#pragma unroll
        for (int it = 0; it < 8; ++it) {
            int j = t + 256 * it;
            int o = j >> 4, c = j & 15, cs = c ^ (o & 15);
            async16(Wrest + o * 128 + cs * 8, &Blds[o * 128 + c * 8]);
        }
#pragma unroll
        for (int it = 0; it < 4; ++it) {
            int j = t + 256 * it;
            int p = j >> 4, c = j & 15, cs = c ^ (p & 15);
            if (p < nrows)
                async16(node_bf + (size_t)(row0 + p) * 128 + cs * 8,
                        &Alds[p * 128 + c * 8]);
        }
        __syncthreads();
        f32x4 acc[2][4];
#pragma unroll
        for (int i = 0; i < 2; ++i)
#pragma unroll
            for (int j = 0; j < 4; ++j) acc[i][j] = (f32x4){0.f, 0.f, 0.f, 0.f};
#pragma unroll
        for (int ks = 0; ks < 4; ++ks) {
            int cs = (ks * 4 + quad) ^ lrow;
            bf16x8 af[2], bfr[4];
#pragma unroll
            for (int i = 0; i < 2; ++i)
                af[i] = *reinterpret_cast<const bf16x8*>(&Alds[(wr + i * 16 + lrow) * 128 + cs * 8]);
#pragma unroll
            for (int j = 0; j < 4; ++j)
                bfr[j] = *reinterpret_cast<const bf16x8*>(&Blds[(wc + j * 16 + lrow) * 128 + cs * 8]);
#pragma unroll
            for (int i = 0; i < 2; ++i)
#pragma unroll
                for (int j = 0; j < 4; ++j)
                    acc[i][j] = __builtin_amdgcn_mfma_f32_16x16x32_bf16(af[i], bfr[j], acc[i][j], 0, 0, 0);
        }
        float br0 = b_res[wc + lrow];
        float br1 = b_res[wc + 16 + lrow];
        float br2 = b_res[wc + 32 + lrow];
        float br3 = b_res[wc + 48 + lrow];
#pragma unroll
        for (int i = 0; i < 2; ++i) {
#pragma unroll
            for (int reg = 0; reg < 4; ++reg) {
                int grow = row0 + wr + i * 16 + quad * 4 + reg;
                if (grow < N_NODES) {
                    float4 v;
                    v.x = fmaxf(acc[i][0][reg] + br0, 0.f);
                    v.y = fmaxf(acc[i][1][reg] + br1, 0.f);
                    v.z = fmaxf(acc[i][2][reg] + br2, 0.f);
                    v.w = fmaxf(acc[i][3][reg] + br3, 0.f);
                    *reinterpret_cast<float4*>(resid + (size_t)grow * 128 + wc + lrow * 4) = v;
                }
            }
        }
        return;
    }

    // ---- edge tile (r5/r9 structure)
    int tid = blockIdx.x - NB_RESID;
    if (tid >= *ntiles_p) return;
    int r = tile_rel[tid], start = tile_start[tid], len = tile_len[tid];
    const unsigned short* Wr = Wt + (size_t)r * 16384;
#pragma unroll
    for (int it = 0; it < 8; ++it) {               // stage W (XOR on source)
        int j = t + 256 * it;
        int o = j >> 4, c = j & 15, cs = c ^ (o & 15);
        async16(Wr + o * 128 + cs * 8, &Blds[o * 128 + c * 8]);
    }
#pragma unroll
    for (int it = 0; it < 4; ++it) {               // stage A (gathered rows)
        int j = t + 256 * it;
        int p = j >> 4, c = j & 15, cs = c ^ (p & 15);
        if (p < len)
            async16(node_bf + (size_t)srcp[start + p] * 128 + cs * 8,
                    &Alds[p * 128 + c * 8]);
    }
    if (t < TM && t < len) {
        snorm[t] = normp[start + t];
        sp2[t] = inv2[start + t];
    }
    __syncthreads();

    f32x4 acc[2][4];
#pragma unroll
    for (int i = 0; i < 2; ++i)
#pragma unroll
        for (int j = 0; j < 4; ++j) acc[i][j] = (f32x4){0.f, 0.f, 0.f, 0.f};
#pragma unroll
    for (int ks = 0; ks < 4; ++ks) {
        int cs = (ks * 4 + quad) ^ lrow;
        bf16x8 af[2], bfr[4];
#pragma unroll
        for (int i = 0; i < 2; ++i)
            af[i] = *reinterpret_cast<const bf16x8*>(&Alds[(wr + i * 16 + lrow) * 128 + cs * 8]);
#pragma unroll
        for (int j = 0; j < 4; ++j)
            bfr[j] = *reinterpret_cast<const bf16x8*>(&Blds[(wc + j * 16 + lrow) * 128 + cs * 8]);
#pragma unroll
        for (int i = 0; i < 2; ++i)
#pragma unroll
            for (int j = 0; j < 4; ++j)
                acc[i][j] = __builtin_amdgcn_mfma_f32_16x16x32_bf16(af[i], bfr[j], acc[i][j], 0, 0, 0);
    }

    // epilogue: scale by norm, pack bf16, PLAIN store (L3-resident t_buf)
#pragma unroll
    for (int i = 0; i < 2; ++i) {
        int m0 = wr + i * 16 + quad * 4;
#pragma unroll
        for (int reg = 0; reg < 4; ++reg) {
            int m = m0 + reg;
            if (m < len) {
                float nm = snorm[m];
                int p2 = sp2[m];
                float2 lo2 = make_float2(acc[i][0][reg] * nm, acc[i][1][reg] * nm);
                float2 hi2 = make_float2(acc[i][2][reg] * nm, acc[i][3][reg] * nm);
                __hip_bfloat162 blo = __float22bfloat162_rn(lo2);
                __hip_bfloat162 bhi = __float22bfloat162_rn(hi2);
                u32x2 st;
                st.x = *reinterpret_cast<unsigned int*>(&blo);
                st.y = *reinterpret_cast<unsigned int*>(&bhi);
                *reinterpret_cast<u32x2*>(t_out + (size_t)p2 * 128 + wc + lrow * 4) = st;
            }
        }
    }
}

// ---------------- K5: wave-per-dst CSR reduce, 8-deep, plain loads ---------
__global__ __launch_bounds__(256) void k_reduce_fused(
    const unsigned short* __restrict__ t, const int* __restrict__ seg,
    const float* __restrict__ resid, const float* __restrict__ h_bias,
    float* __restrict__ h, float* __restrict__ colsum, float* __restrict__ colsumsq) {
    __shared__ float cs1[128], cs2[128], sbias[128];
    if (threadIdx.x < 128) {
        cs1[threadIdx.x] = 0.f; cs2[threadIdx.x] = 0.f;
        sbias[threadIdx.x] = h_bias[unperm(threadIdx.x)];
    }
    __syncthreads();
    int w = threadIdx.x >> 6, lane = threadIdx.x & 63;
    int g = lane >> 4, c = lane & 15;
    for (int k = 0; k < 4; ++k) {
        int d = blockIdx.x * 16 + k * 4 + w;
        int a = seg[d], b = seg[d + 1];
        float s[8];
#pragma unroll
        for (int kk = 0; kk < 8; ++kk) s[kk] = 0.f;
        int q = a + g;
        for (; q + 28 < b; q += 32) {
            u32x4 v0 = *reinterpret_cast<const u32x4*>(t + (size_t)q * 128 + c * 8);
            u32x4 v1 = *reinterpret_cast<const u32x4*>(t + (size_t)(q + 4) * 128 + c * 8);
            u32x4 v2 = *reinterpret_cast<const u32x4*>(t + (size_t)(q + 8) * 128 + c * 8);
            u32x4 v3 = *reinterpret_cast<const u32x4*>(t + (size_t)(q + 12) * 128 + c * 8);
            u32x4 v4 = *reinterpret_cast<const u32x4*>(t + (size_t)(q + 16) * 128 + c * 8);
            u32x4 v5 = *reinterpret_cast<const u32x4*>(t + (size_t)(q + 20) * 128 + c * 8);
            u32x4 v6 = *reinterpret_cast<const u32x4*>(t + (size_t)(q + 24) * 128 + c * 8);
            u32x4 v7 = *reinterpret_cast<const u32x4*>(t + (size_t)(q + 28) * 128 + c * 8);
#pragma unroll
            for (int kk = 0; kk < 4; ++kk) {
                s[2 * kk]     += bf2f_lo(v0[kk]) + bf2f_lo(v1[kk]) + bf2f_lo(v2[kk]) + bf2f_lo(v3[kk])
                               + bf2f_lo(v4[kk]) + bf2f_lo(v5[kk]) + bf2f_lo(v6[kk]) + bf2f_lo(v7[kk]);
                s[2 * kk + 1] += bf2f_hi(v0[kk]) + bf2f_hi(v1[kk]) + bf2f_hi(v2[kk]) + bf2f_hi(v3[kk])
                               + bf2f_hi(v4[kk]) + bf2f_hi(v5[kk]) + bf2f_hi(v6[kk]) + bf2f_hi(v7[kk]);
            }
        }
        for (; q < b; q += 4) {
            u32x4 v = *reinterpret_cast<const u32x4*>(t + (size_t)q * 128 + c * 8);
#pragma unroll
            for (int kk = 0; kk < 4; ++kk) {
                s[2 * kk]     += bf2f_lo(v[kk]);
                s[2 * kk + 1] += bf2f_hi(v[kk]);
            }
        }
#pragma unroll
        for (int kk = 0; kk < 8; ++kk) {
            s[kk] += __shfl_xor(s[kk], 16);
            s[kk] += __shfl_xor(s[kk], 32);
        }
        if (g == 0) {
            const float* rp = resid + (size_t)d * 128 + c * 8;
            float4 r0 = *reinterpret_cast<const float4*>(rp);
            float4 r1 = *reinterpret_cast<const float4*>(rp + 4);
            float rr[8] = {r0.x, r0.y, r0.z, r0.w, r1.x, r1.y, r1.z, r1.w};
            float v[8];
#pragma unroll
            for (int kk = 0; kk < 8; ++kk)
                v[kk] = fmaxf(s[kk] + sbias[c * 8 + kk], 0.f) + rr[kk];
            float* hp = h + (size_t)d * 128 + c * 8;
            *reinterpret_cast<float4*>(hp)     = make_float4(v[0], v[1], v[2], v[3]);
            *reinterpret_cast<float4*>(hp + 4) = make_float4(v[4], v[5], v[6], v[7]);
#pragma unroll
            for (int kk = 0; kk < 8; ++kk) {
                atomicAdd(&cs1[c * 8 + kk], v[kk]);
                atomicAdd(&cs2[c * 8 + kk], v[kk] * v[kk]);
            }
        }
    }
    __syncthreads();
    if (threadIdx.x < 128) {
        atomicAdd(&colsum[threadIdx.x], cs1[threadIdx.x]);
        atomicAdd(&colsumsq[threadIdx.x], cs2[threadIdx.x]);
    }
}

// ---------------- K6: BN apply + unpermute to natural cols -----------------
__global__ void k_bn(float* __restrict__ h, const float* __restrict__ colsum,
                     const float* __restrict__ colsumsq, const float* __restrict__ gamma,
                     const float* __restrict__ beta) {
    __shared__ float sc[128], sh[128], tile[8][128];
    int t = threadIdx.x;
    if (t < 128) {
        int n = unperm(t);
        float m = colsum[t] * (1.f / N_NODES);
        float var = colsumsq[t] * (1.f / N_NODES) - m * m;
        float s = gamma[n] * rsqrtf(var + 1e-5f);
        sc[t] = s;
        sh[t] = beta[n] - m * s;
    }
    __syncthreads();
    int r = t >> 5;
    int p0 = (t & 31) * 4;
    int n0 = (p0 & 64) + ((p0 >> 2) & 15);
    for (int row0 = blockIdx.x * 8; row0 < N_NODES; row0 += gridDim.x * 8) {
        int row = row0 + r;
        float4 v = make_float4(0.f, 0.f, 0.f, 0.f);
        if (row < N_NODES) v = *reinterpret_cast<float4*>(h + (size_t)row * 128 + p0);
        v.x = v.x * sc[p0] + sh[p0];
        v.y = v.y * sc[p0 + 1] + sh[p0 + 1];
        v.z = v.z * sc[p0 + 2] + sh[p0 + 2];
        v.w = v.w * sc[p0 + 3] + sh[p0 + 3];
        tile[r][n0]      = v.x;
        tile[r][n0 + 16] = v.y;
        tile[r][n0 + 32] = v.z;
        tile[r][n0 + 48] = v.w;
        __syncthreads();
        if (row < N_NODES)
            *reinterpret_cast<float4*>(h + (size_t)row * 128 + p0) =
                *reinterpret_cast<float4*>(&tile[r][p0]);
        __syncthreads();
    }
}

extern "C" void kernel_launch(void* const* d_in, const int* in_sizes, int n_in,
                              void* d_out, int out_size, void* d_ws, size_t ws_size,
                              hipStream_t stream) {
    (void)in_sizes; (void)n_in; (void)out_size; (void)ws_size;
    const float* node_feats = (const float*)d_in[0];
    const int* src    = (const int*)d_in[1];
    const int* dst    = (const int*)d_in[2];
    const int* etype  = (const int*)d_in[3];
    const float* norm = (const float*)d_in[4];
    const float* basis = (const float*)d_in[5];
    const float* comp  = (const float*)d_in[6];
    const float* h_bias = (const float*)d_in[7];
    const float* W_res  = (const float*)d_in[8];
    const float* b_res  = (const float*)d_in[9];
    const float* gamma  = (const float*)d_in[10];
    const float* beta   = (const float*)d_in[11];

    char* ws = (char*)d_ws;
    int* ghist      = (int*)(ws + 0);
    int* cnt        = (int*)(ws + 1024);
    int* ntiles_p   = (int*)(ws + 2048);
    float* colsum   = (float*)(ws + 2560);
    float* colsumsq = (float*)(ws + 3072);
    int* gh2        = (int*)(ws + 8192);       // 80000 -> 88192
    int* tile_rel   = (int*)(ws + 88192);      // 40960
    int* tile_start = (int*)(ws + 129152);     // 40960
    int* tile_len   = (int*)(ws + 170112);     // 40960 -> 211072
    unsigned short* Wt      = (unsigned short*)(ws + 211072);    // 2129920 -> 2340992
    unsigned short* Wrest   = (unsigned short*)(ws + 2340992);   // 32768   -> 2373760
    unsigned short* node_bf = (unsigned short*)(ws + 2373760);   // 5120000 -> 7493760
    int* srcp       = (int*)(ws + 7493760);    // 2560000 -> 10053760
    float* normp    = (float*)(ws + 10053760); // 2560000 -> 12613760
    int* inv2       = (int*)(ws + 12613760);   // 2560000 -> 15173760
    float* resid    = (float*)(ws + 15173760); // 10240000 -> 25413760
    int* seg        = (int*)(ws + 25413760);   // 80004 -> 25493764, pad
    int* cnt2       = (int*)(ws + 25493776);   // 80000 -> 25573776
    const long T_BASE = 25573776L;             // 16B aligned
    float* W32      = (float*)(ws + T_BASE);   // aliased: dead before conv
    unsigned short* t_buf = (unsigned short*)(ws + T_BASE);      // 163.84 MB
    float* hacc = (float*)d_out;

    hipMemsetAsync(ws, 0, 88192, stream);
    k_prep1<<<3332, 256, 0, stream>>>(comp, basis, W32, etype, dst, ghist, gh2,
                                      node_feats, node_bf);
    k_prep3<<<345, 256, 0, stream>>>(gh2, cnt2, seg, ghist, cnt, ntiles_p,
                                     tile_rel, tile_start, tile_len,
                                     W32, Wt, W_res, Wrest);
    k_scatter2<<<(E_EDGES + SCAT_CH - 1) / SCAT_CH, 256, 0, stream>>>(
        etype, src, dst, norm, cnt, cnt2, srcp, normp, inv2);
    k_conv_gemm<<<NB_RESID + MAX_TILES, 256, 0, stream>>>(
        tile_rel, tile_start, tile_len, ntiles_p, srcp, normp, node_bf,
        Wt, Wrest, b_res, inv2, t_buf, resid);
    k_reduce_fused<<<N_NODES / 16, 256, 0, stream>>>(t_buf, seg, resid, h_bias,
                                                     hacc, colsum, colsumsq);
    k_bn<<<2500, 256, 0, stream>>>(hacc, colsum, colsumsq, gamma, beta);
}